// Round 19
// baseline (248.884 us; speedup 1.0000x reference)
//
#include <hip/hip_runtime.h>

#define NT 512
#define SCL (1.0f / 8192.0f)
#define PI_F 3.14159265358979323846f

// XOR swizzle: bijective involution on [0,4096) float4 indices.
__device__ __forceinline__ int P(int i) { return i ^ ((i >> 5) & 31); }

__device__ __forceinline__ float2 cmul(float2 a, float2 b) {
  return make_float2(a.x * b.x - a.y * b.y, a.x * b.y + a.y * b.x);
}
__device__ __forceinline__ float2 csqr(float2 a) {
  return make_float2(a.x * a.x - a.y * a.y, 2.f * a.x * a.y);
}
__device__ __forceinline__ float2 cadd(float2 a, float2 b) { return make_float2(a.x + b.x, a.y + b.y); }
__device__ __forceinline__ float2 csub(float2 a, float2 b) { return make_float2(a.x - b.x, a.y - b.y); }
__device__ __forceinline__ float2 cmuli (float2 a) { return make_float2(-a.y,  a.x); } // *(+i)
__device__ __forceinline__ float2 cmulmi(float2 a) { return make_float2( a.y, -a.x); } // *(-i)

constexpr float RT2 = 0.70710678118654752440f;
constexpr float CQ1 = 0.92387953251128675613f; // cos(pi/8)
constexpr float SQ1 = 0.38268343236508977173f; // sin(pi/8)
// C8[k] = W8^k = e^{-i pi k/4}
constexpr float C8x[4] = {1.f,  RT2, 0.f, -RT2};
constexpr float C8y[4] = {0.f, -RT2, -1.f, -RT2};
// C16[k] = W16^k = e^{-i pi k/8} — used as W_8192^{512k} in the fused loads
constexpr float C16x[8] = {1.f,  CQ1,  RT2,  SQ1, 0.f, -SQ1, -RT2, -CQ1};
constexpr float C16y[8] = {0.f, -SQ1, -RT2, -CQ1, -1.f, -CQ1, -RT2, -SQ1};

// In-register 8-point DIF, stages at register strides 4,2,1 (R7/R14-verified).
// Stage stride s uses twiddle b^{4/s} * W_{2s}^{j mod s}; UNIT means b == 1.
template<bool UNIT>
__device__ __forceinline__ void r8_fwd(float2* e, float2 b) {
  float2 b2, b4;
  if (!UNIT) { b2 = csqr(b); b4 = csqr(b2); }
  #pragma unroll
  for (int j = 0; j < 4; ++j) {
    float2 u = e[j], v = e[j + 4];
    float2 d = csub(u, v);
    e[j] = cadd(u, v);
    float2 c8 = make_float2(C8x[j], C8y[j]);
    if (UNIT) e[j + 4] = (j == 0) ? d : cmul(d, c8);
    else      e[j + 4] = cmul(d, (j == 0) ? b : cmul(b, c8));
  }
  #pragma unroll
  for (int o = 0; o < 8; o += 4) {
    #pragma unroll
    for (int j = 0; j < 2; ++j) {
      float2 u = e[o + j], v = e[o + j + 2];
      float2 d = csub(u, v);
      e[o + j] = cadd(u, v);
      if (UNIT) e[o + j + 2] = (j == 0) ? d : cmulmi(d);
      else      e[o + j + 2] = cmul(d, (j == 0) ? b2 : cmulmi(b2));
    }
  }
  #pragma unroll
  for (int o = 0; o < 8; o += 2) {
    float2 u = e[o], v = e[o + 1];
    float2 d = csub(u, v);
    e[o] = cadd(u, v);
    e[o + 1] = UNIT ? d : cmul(d, b4);
  }
}

// In-register 8-point DIT inverse, stages at strides 1,2,4. g = conj(beta).
template<bool UNIT>
__device__ __forceinline__ void r8_inv(float2* e, float2 g) {
  float2 g2, g4;
  if (!UNIT) { g2 = csqr(g); g4 = csqr(g2); }
  #pragma unroll
  for (int o = 0; o < 8; o += 2) {
    float2 t = UNIT ? e[o + 1] : cmul(e[o + 1], g4);
    float2 u = e[o];
    e[o] = cadd(u, t); e[o + 1] = csub(u, t);
  }
  #pragma unroll
  for (int o = 0; o < 8; o += 4) {
    #pragma unroll
    for (int j = 0; j < 2; ++j) {
      float2 v = e[o + j + 2];
      float2 t;
      if (UNIT) t = (j == 0) ? v : cmuli(v);
      else      t = cmul(v, (j == 0) ? g2 : cmuli(g2));
      float2 u = e[o + j];
      e[o + j] = cadd(u, t); e[o + j + 2] = csub(u, t);
    }
  }
  #pragma unroll
  for (int j = 0; j < 4; ++j) {
    float2 v = e[j + 4];
    float2 t;
    float2 c8c = make_float2(C8x[j], -C8y[j]);
    if (UNIT) t = (j == 0) ? v : cmul(v, c8c);
    else      t = cmul(v, (j == 0) ? g : cmul(g, c8c));
    float2 u = e[j];
    e[j] = cadd(u, t); e[j + 4] = csub(u, t);
  }
}

// Dual radix-8 trips on the float4-packed buffer: .xy = lo half, .zw = hi half.
// One ds_read_b128/ds_write_b128 per element pair; twiddle regs shared.
__device__ __forceinline__ void d8f(float4* cb, int base, int G, float2 b) {
  float2 lo[8], hi[8];
  #pragma unroll
  for (int j = 0; j < 8; ++j) {
    float4 q = cb[P(base + G * j)];
    lo[j] = make_float2(q.x, q.y);
    hi[j] = make_float2(q.z, q.w);
  }
  r8_fwd<false>(lo, b);
  r8_fwd<false>(hi, b);
  #pragma unroll
  for (int j = 0; j < 8; ++j)
    cb[P(base + G * j)] = make_float4(lo[j].x, lo[j].y, hi[j].x, hi[j].y);
}

__device__ __forceinline__ void d8i(float4* cb, int base, int G, float2 g) {
  float2 lo[8], hi[8];
  #pragma unroll
  for (int j = 0; j < 8; ++j) {
    float4 q = cb[P(base + G * j)];
    lo[j] = make_float2(q.x, q.y);
    hi[j] = make_float2(q.z, q.w);
  }
  r8_inv<false>(lo, g);
  r8_inv<false>(hi, g);
  #pragma unroll
  for (int j = 0; j < 8; ++j)
    cb[P(base + G * j)] = make_float4(lo[j].x, lo[j].y, hi[j].x, hi[j].y);
}

// K2: ONE WG per channel d (R19). The WG computes T-hat (both 4096-pt halves)
// and keeps it ENTIRELY in registers — the t-FFT's MID-fwd output at position
// tid*8+j is exactly the value the conv MID multiplies at the same position —
// then runs both passes. Kills the that8h kernel and the 64+64 MB ThG global
// round trip. Structure per section is the R17/R18-verified 7-phase parallel-
// halves pipeline on the float4-packed cb (.xy lo, .zw hi).
// t-FFT: [load t + A], [B], [C], [MID-fwd -> thL/thH regs, scaled].
// Per pass: [load x + A], [B], [C], [MID thL/thH], [C'], [B'],
// [A' in regs + combine y = u + v*conj(W_8192^n) + store].
__global__ __launch_bounds__(NT)
void fftconv(float* __restrict__ xT, const float* __restrict__ tT) {
  __shared__ float4 cb[4096];   // 64 KiB packed: .xy lo half, .zw hi half
  const int tid = threadIdx.x;
  const int d = blockIdx.x;

  const int baseB = ((tid >> 6) << 9) + (tid & 63);
  const int baseC = ((tid >> 3) << 6) + (tid & 7);
  const float2 ONE = make_float2(1.f, 0.f);

  float s0, c0; __sincosf(-PI_F * (float)tid / 2048.f, &s0, &c0);
  const float2 bA = make_float2(c0, s0);            // W_4096^tid
  const float2 gA = make_float2(c0, -s0);
  float s1, c1; __sincosf(-PI_F * (float)(tid & 63) / 256.f, &s1, &c1);
  const float2 bB = make_float2(c1, s1);            // W_512^(tid&63)
  const float2 gB = make_float2(c1, -s1);
  float s2, c2; __sincosf(-PI_F * (float)(tid & 7) / 32.f, &s2, &c2);
  const float2 bC = make_float2(c2, s2);            // W_64^(tid&7)
  const float2 gC = make_float2(c2, -s2);
  float sw, cw; __sincosf(-PI_F * (float)tid / 4096.f, &sw, &cw);
  const float2 whi  = make_float2(cw, sw);          // W_8192^tid
  const float2 whic = make_float2(cw, -sw);

  // ================= T-hat: 4 phases, result pinned in registers ===========
  float2 thL[8], thH[8];
  {
    const float* tp = tT + (size_t)d * 4096;
    float tv[8];
    #pragma unroll
    for (int j = 0; j < 8; ++j) tv[j] = tp[tid + 512 * j];
    float2 lo[8], hi[8];
    #pragma unroll
    for (int j = 0; j < 8; ++j) {
      lo[j] = make_float2(tv[j], 0.f);
      float2 w = (j == 0) ? whi : cmul(whi, make_float2(C16x[j], C16y[j])); // W_8192^n
      hi[j] = make_float2(tv[j] * w.x, tv[j] * w.y);
    }
    r8_fwd<false>(lo, bA);
    r8_fwd<false>(hi, bA);
    #pragma unroll
    for (int j = 0; j < 8; ++j)
      cb[P(tid + 512 * j)] = make_float4(lo[j].x, lo[j].y, hi[j].x, hi[j].y);
  }
  __syncthreads();
  d8f(cb, baseB, 64, bB);  __syncthreads();
  d8f(cb, baseC, 8, bC);   __syncthreads();
  {
    float2 lo[8], hi[8];
    #pragma unroll
    for (int j = 0; j < 8; ++j) {
      float4 q = cb[P(tid * 8 + j)];
      lo[j] = make_float2(q.x, q.y);
      hi[j] = make_float2(q.z, q.w);
    }
    r8_fwd<true>(lo, ONE);
    r8_fwd<true>(hi, ONE);
    #pragma unroll
    for (int j = 0; j < 8; ++j) {
      thL[j] = make_float2(lo[j].x * SCL, lo[j].y * SCL);
      thH[j] = make_float2(hi[j].x * SCL, hi[j].y * SCL);
    }
  }
  __syncthreads();   // cb reads done; pass loop may overwrite

  // ================= two passes, 7 phases each =============================
  #pragma unroll 1
  for (int pass = 0; pass < 2; ++pass) {
    float* r0 = xT + ((size_t)(2 * pass)     * 1024 + d) * 4096;
    float* r1 = xT + ((size_t)(2 * pass + 1) * 1024 + d) * 4096;

    // ---- Phase 1: load x ONCE; trip A on both halves (lo: x, hi: x*W) ----
    {
      float2 xv[8], m[8];
      #pragma unroll
      for (int j = 0; j < 8; ++j) {
        int n = tid + 512 * j;
        xv[j] = make_float2(r0[n], r1[n]);
      }
      #pragma unroll
      for (int j = 0; j < 8; ++j) {
        float2 w = (j == 0) ? whi : cmul(whi, make_float2(C16x[j], C16y[j])); // W_8192^n
        m[j] = cmul(xv[j], w);
      }
      r8_fwd<false>(xv, bA);   // lo-half trip A
      r8_fwd<false>(m, bA);    // hi-half trip A
      #pragma unroll
      for (int j = 0; j < 8; ++j)
        cb[P(tid + 512 * j)] = make_float4(xv[j].x, xv[j].y, m[j].x, m[j].y);
    }
    __syncthreads();

    // ---- Phase 2: B on both halves ----
    d8f(cb, baseB, 64, bB);
    __syncthreads();

    // ---- Phase 3: C on both halves ----
    d8f(cb, baseC, 8, bC);
    __syncthreads();

    // ---- Phase 4: MID on both halves (unit fwd + That* + unit inv) ----
    {
      float2 lo[8], hi[8];
      #pragma unroll
      for (int j = 0; j < 8; ++j) {
        float4 q = cb[P(tid * 8 + j)];
        lo[j] = make_float2(q.x, q.y);
        hi[j] = make_float2(q.z, q.w);
      }
      r8_fwd<true>(lo, ONE);
      r8_fwd<true>(hi, ONE);
      #pragma unroll
      for (int j = 0; j < 8; ++j) {
        lo[j] = cmul(lo[j], thL[j]);
        hi[j] = cmul(hi[j], thH[j]);
      }
      r8_inv<true>(lo, ONE);
      r8_inv<true>(hi, ONE);
      #pragma unroll
      for (int j = 0; j < 8; ++j)
        cb[P(tid * 8 + j)] = make_float4(lo[j].x, lo[j].y, hi[j].x, hi[j].y);
    }
    __syncthreads();

    // ---- Phase 5: C' on both halves ----
    d8i(cb, baseC, 8, gC);
    __syncthreads();

    // ---- Phase 6: B' on both halves ----
    d8i(cb, baseB, 64, gB);
    __syncthreads();

    // ---- Phase 7: A' in registers on both halves + combine + store ----
    {
      float2 u[8], v[8];
      #pragma unroll
      for (int j = 0; j < 8; ++j) {
        float4 q = cb[P(tid + 512 * j)];
        u[j] = make_float2(q.x, q.y);
        v[j] = make_float2(q.z, q.w);
      }
      r8_inv<false>(u, gA);
      r8_inv<false>(v, gA);
      // final h=4096 inverse stage fused into the store: y = u + v*conj(W_8192^n)
      #pragma unroll
      for (int k = 0; k < 8; ++k) {
        float2 wc = (k == 0) ? whic : cmul(whic, make_float2(C16x[k], -C16y[k]));
        float2 t = cmul(v[k], wc);
        int n = tid + 512 * k;
        r0[n] = u[k].x + t.x;
        r1[n] = u[k].y + t.y;
      }
    }
    __syncthreads();   // cb reads done; next pass may overwrite
  }
}

// 64x64 tile transpose, 256 threads, float4 global I/O, padded LDS.
// At ~6.6 TB/s measured (R7) — HBM roofline; leave as is.
__global__ __launch_bounds__(256)
void transpose64(const float* __restrict__ src, float* __restrict__ dst, int R, int C) {
  __shared__ float tile[64][65];
  int t  = threadIdx.x;
  int c4 = t & 15;
  int r  = t >> 4;
  size_t slab = (size_t)blockIdx.z * (size_t)R * (size_t)C;
  const float* s = src + slab;
  float* dd = dst + slab;
  int col0 = blockIdx.x * 64, row0 = blockIdx.y * 64;
  #pragma unroll
  for (int k = 0; k < 4; ++k) {
    int rr = r + 16 * k;
    const float4 v = *(const float4*)(s + (size_t)(row0 + rr) * C + col0 + 4 * c4);
    tile[rr][4 * c4 + 0] = v.x;
    tile[rr][4 * c4 + 1] = v.y;
    tile[rr][4 * c4 + 2] = v.z;
    tile[rr][4 * c4 + 3] = v.w;
  }
  __syncthreads();
  #pragma unroll
  for (int k = 0; k < 4; ++k) {
    int cc = r + 16 * k;
    float4 w;
    w.x = tile[4 * c4 + 0][cc];
    w.y = tile[4 * c4 + 1][cc];
    w.z = tile[4 * c4 + 2][cc];
    w.w = tile[4 * c4 + 3][cc];
    *(float4*)(dd + (size_t)(col0 + cc) * R + row0 + 4 * c4) = w;
  }
}

extern "C" void kernel_launch(void* const* d_in, const int* in_sizes, int n_in,
                              void* d_out, int out_size, void* d_ws, size_t ws_size,
                              hipStream_t stream) {
  const float* x = (const float*)d_in[0];   // (4, 4096, 1024)
  const float* t = (const float*)d_in[1];   // (4096, 1024)
  float* out = (float*)d_out;               // (4, 4096, 1024)
  float* ws  = (float*)d_ws;
  float* xT  = ws;                                   // (4, 1024, 4096)  64 MB
  float* tT  = ws + (size_t)4 * 1024 * 4096;         // (1024, 4096)     16 MB

  transpose64<<<dim3(16, 64, 4), 256, 0, stream>>>(x, xT, 4096, 1024);
  transpose64<<<dim3(16, 64, 1), 256, 0, stream>>>(t, tT, 4096, 1024);

  fftconv<<<dim3(1024), NT, 0, stream>>>(xT, tT);

  transpose64<<<dim3(64, 16, 4), 256, 0, stream>>>(xT, out, 1024, 4096);
}

// Round 20
// 148.689 us; speedup vs baseline: 1.6739x; 1.6739x over previous
//
#include <hip/hip_runtime.h>

#define NT 512
#define SCL (1.0f / 8192.0f)
#define PI_F 3.14159265358979323846f

// XOR swizzle: bijective involution on [0,4096) float4 indices.
__device__ __forceinline__ int P(int i) { return i ^ ((i >> 5) & 31); }

__device__ __forceinline__ float2 cmul(float2 a, float2 b) {
  return make_float2(a.x * b.x - a.y * b.y, a.x * b.y + a.y * b.x);
}
__device__ __forceinline__ float2 csqr(float2 a) {
  return make_float2(a.x * a.x - a.y * a.y, 2.f * a.x * a.y);
}
__device__ __forceinline__ float2 cadd(float2 a, float2 b) { return make_float2(a.x + b.x, a.y + b.y); }
__device__ __forceinline__ float2 csub(float2 a, float2 b) { return make_float2(a.x - b.x, a.y - b.y); }
__device__ __forceinline__ float2 cmuli (float2 a) { return make_float2(-a.y,  a.x); } // *(+i)
__device__ __forceinline__ float2 cmulmi(float2 a) { return make_float2( a.y, -a.x); } // *(-i)

constexpr float RT2 = 0.70710678118654752440f;
constexpr float CQ1 = 0.92387953251128675613f; // cos(pi/8)
constexpr float SQ1 = 0.38268343236508977173f; // sin(pi/8)
// C8[k] = W8^k = e^{-i pi k/4}
constexpr float C8x[4] = {1.f,  RT2, 0.f, -RT2};
constexpr float C8y[4] = {0.f, -RT2, -1.f, -RT2};
// C16[k] = W16^k = e^{-i pi k/8} — used as W_8192^{512k} in the fused loads
constexpr float C16x[8] = {1.f,  CQ1,  RT2,  SQ1, 0.f, -SQ1, -RT2, -CQ1};
constexpr float C16y[8] = {0.f, -SQ1, -RT2, -CQ1, -1.f, -CQ1, -RT2, -SQ1};

// In-register 8-point DIF, stages at register strides 4,2,1 (R7/R14-verified).
// Stage stride s uses twiddle b^{4/s} * W_{2s}^{j mod s}; UNIT means b == 1.
template<bool UNIT>
__device__ __forceinline__ void r8_fwd(float2* e, float2 b) {
  float2 b2, b4;
  if (!UNIT) { b2 = csqr(b); b4 = csqr(b2); }
  #pragma unroll
  for (int j = 0; j < 4; ++j) {
    float2 u = e[j], v = e[j + 4];
    float2 d = csub(u, v);
    e[j] = cadd(u, v);
    float2 c8 = make_float2(C8x[j], C8y[j]);
    if (UNIT) e[j + 4] = (j == 0) ? d : cmul(d, c8);
    else      e[j + 4] = cmul(d, (j == 0) ? b : cmul(b, c8));
  }
  #pragma unroll
  for (int o = 0; o < 8; o += 4) {
    #pragma unroll
    for (int j = 0; j < 2; ++j) {
      float2 u = e[o + j], v = e[o + j + 2];
      float2 d = csub(u, v);
      e[o + j] = cadd(u, v);
      if (UNIT) e[o + j + 2] = (j == 0) ? d : cmulmi(d);
      else      e[o + j + 2] = cmul(d, (j == 0) ? b2 : cmulmi(b2));
    }
  }
  #pragma unroll
  for (int o = 0; o < 8; o += 2) {
    float2 u = e[o], v = e[o + 1];
    float2 d = csub(u, v);
    e[o] = cadd(u, v);
    e[o + 1] = UNIT ? d : cmul(d, b4);
  }
}

// In-register 8-point DIT inverse, stages at strides 1,2,4. g = conj(beta).
template<bool UNIT>
__device__ __forceinline__ void r8_inv(float2* e, float2 g) {
  float2 g2, g4;
  if (!UNIT) { g2 = csqr(g); g4 = csqr(g2); }
  #pragma unroll
  for (int o = 0; o < 8; o += 2) {
    float2 t = UNIT ? e[o + 1] : cmul(e[o + 1], g4);
    float2 u = e[o];
    e[o] = cadd(u, t); e[o + 1] = csub(u, t);
  }
  #pragma unroll
  for (int o = 0; o < 8; o += 4) {
    #pragma unroll
    for (int j = 0; j < 2; ++j) {
      float2 v = e[o + j + 2];
      float2 t;
      if (UNIT) t = (j == 0) ? v : cmuli(v);
      else      t = cmul(v, (j == 0) ? g2 : cmuli(g2));
      float2 u = e[o + j];
      e[o + j] = cadd(u, t); e[o + j + 2] = csub(u, t);
    }
  }
  #pragma unroll
  for (int j = 0; j < 4; ++j) {
    float2 v = e[j + 4];
    float2 t;
    float2 c8c = make_float2(C8x[j], -C8y[j]);
    if (UNIT) t = (j == 0) ? v : cmul(v, c8c);
    else      t = cmul(v, (j == 0) ? g : cmul(g, c8c));
    float2 u = e[j];
    e[j] = cadd(u, t); e[j + 4] = csub(u, t);
  }
}

// Dual radix-8 trips on the float4-packed buffer: .xy = lo half, .zw = hi half.
// One ds_read_b128/ds_write_b128 per element pair; twiddle regs shared.
__device__ __forceinline__ void d8f(float4* cb, int base, int G, float2 b) {
  float2 lo[8], hi[8];
  #pragma unroll
  for (int j = 0; j < 8; ++j) {
    float4 q = cb[P(base + G * j)];
    lo[j] = make_float2(q.x, q.y);
    hi[j] = make_float2(q.z, q.w);
  }
  r8_fwd<false>(lo, b);
  r8_fwd<false>(hi, b);
  #pragma unroll
  for (int j = 0; j < 8; ++j)
    cb[P(base + G * j)] = make_float4(lo[j].x, lo[j].y, hi[j].x, hi[j].y);
}

__device__ __forceinline__ void d8i(float4* cb, int base, int G, float2 g) {
  float2 lo[8], hi[8];
  #pragma unroll
  for (int j = 0; j < 8; ++j) {
    float4 q = cb[P(base + G * j)];
    lo[j] = make_float2(q.x, q.y);
    hi[j] = make_float2(q.z, q.w);
  }
  r8_inv<false>(lo, g);
  r8_inv<false>(hi, g);
  #pragma unroll
  for (int j = 0; j < 8; ++j)
    cb[P(base + G * j)] = make_float4(lo[j].x, lo[j].y, hi[j].x, hi[j].y);
}

// K2a: both T-hat halves in one WG, float4-packed (R17 structure + R18 pack).
// half-lo input = t[n]; half-hi = t[n]*W_8192^n. 4096 = 8^4: A(fused load),
// B(G=64), C(G=8), MID-fwd + scaled store interleaved:
// ThG4[d*4096 + tid + 512*j] = {T-lo, T-hi} (fftconv reads it back as float4).
__global__ __launch_bounds__(NT)
void that8h(const float* __restrict__ tT, float4* __restrict__ ThG) {
  __shared__ float4 cb[4096];   // 64 KiB packed
  const int tid = threadIdx.x;
  const int d = blockIdx.x;

  const int baseB = ((tid >> 6) << 9) + (tid & 63);
  const int baseC = ((tid >> 3) << 6) + (tid & 7);

  float s0, c0; __sincosf(-PI_F * (float)tid / 2048.f, &s0, &c0);
  const float2 bA = make_float2(c0, s0);            // W_4096^tid
  float s1, c1; __sincosf(-PI_F * (float)(tid & 63) / 256.f, &s1, &c1);
  const float2 bB = make_float2(c1, s1);            // W_512^(tid&63)
  float s2, c2; __sincosf(-PI_F * (float)(tid & 7) / 32.f, &s2, &c2);
  const float2 bC = make_float2(c2, s2);            // W_64^(tid&7)
  float sw, cw; __sincosf(-PI_F * (float)tid / 4096.f, &sw, &cw);
  const float2 whi = make_float2(cw, sw);           // W_8192^tid

  const float* tp = tT + (size_t)d * 4096;
  {
    float tv[8];
    #pragma unroll
    for (int j = 0; j < 8; ++j) tv[j] = tp[tid + 512 * j];
    float2 lo[8], hi[8];
    #pragma unroll
    for (int j = 0; j < 8; ++j) {
      lo[j] = make_float2(tv[j], 0.f);
      float2 w = (j == 0) ? whi : cmul(whi, make_float2(C16x[j], C16y[j])); // W_8192^n
      hi[j] = make_float2(tv[j] * w.x, tv[j] * w.y);
    }
    r8_fwd<false>(lo, bA);
    r8_fwd<false>(hi, bA);
    #pragma unroll
    for (int j = 0; j < 8; ++j)
      cb[P(tid + 512 * j)] = make_float4(lo[j].x, lo[j].y, hi[j].x, hi[j].y);
  }
  __syncthreads();
  d8f(cb, baseB, 64, bB);  __syncthreads();
  d8f(cb, baseC, 8, bC);   __syncthreads();
  {
    float2 lo[8], hi[8];
    #pragma unroll
    for (int j = 0; j < 8; ++j) {
      float4 q = cb[P(tid * 8 + j)];
      lo[j] = make_float2(q.x, q.y);
      hi[j] = make_float2(q.z, q.w);
    }
    r8_fwd<true>(lo, make_float2(1.f, 0.f));
    r8_fwd<true>(hi, make_float2(1.f, 0.f));
    float4* thg = ThG + (size_t)d * 4096;
    #pragma unroll
    for (int j = 0; j < 8; ++j)
      thg[tid + 512 * j] = make_float4(lo[j].x * SCL, lo[j].y * SCL,
                                       hi[j].x * SCL, hi[j].y * SCL);
  }
}

// K2b: one WG per (pass, channel d). R18 structure unchanged; R20: grid is
// (2, 1024) with pass = blockIdx.x, d = blockIdx.y, so the two passes of a
// channel dispatch back-to-back and pass 1's ThG read hits L2/L3 hot
// (R18's x-major (1024,2) grid ran all pass-0 WGs first -> ThG evicted,
// ~34 MB extra FETCH).
// Phases: [load + A both], [B], [th prefetch + C], [MID], [C'], [B'],
// [A' in regs + combine y = u + v*conj(W_8192^n) + store].
__global__ __launch_bounds__(NT)
void fftconv(float* __restrict__ xT, const float4* __restrict__ ThG) {
  __shared__ float4 cb[4096];   // 64 KiB packed: .xy lo half, .zw hi half
  const int tid = threadIdx.x;
  const int pass = blockIdx.x;
  const int d = blockIdx.y;

  const int baseB = ((tid >> 6) << 9) + (tid & 63);
  const int baseC = ((tid >> 3) << 6) + (tid & 7);
  const float2 ONE = make_float2(1.f, 0.f);

  float s0, c0; __sincosf(-PI_F * (float)tid / 2048.f, &s0, &c0);
  const float2 bA = make_float2(c0, s0);            // W_4096^tid
  const float2 gA = make_float2(c0, -s0);
  float s1, c1; __sincosf(-PI_F * (float)(tid & 63) / 256.f, &s1, &c1);
  const float2 bB = make_float2(c1, s1);            // W_512^(tid&63)
  const float2 gB = make_float2(c1, -s1);
  float s2, c2; __sincosf(-PI_F * (float)(tid & 7) / 32.f, &s2, &c2);
  const float2 bC = make_float2(c2, s2);            // W_64^(tid&7)
  const float2 gC = make_float2(c2, -s2);
  float sw, cw; __sincosf(-PI_F * (float)tid / 4096.f, &sw, &cw);
  const float2 whi  = make_float2(cw, sw);          // W_8192^tid
  const float2 whic = make_float2(cw, -sw);

  float* r0 = xT + ((size_t)(2 * pass)     * 1024 + d) * 4096;
  float* r1 = xT + ((size_t)(2 * pass + 1) * 1024 + d) * 4096;
  const float4* thg = ThG + (size_t)d * 4096;

  // ---- Phase 1: load x ONCE; trip A on both halves (lo: x, hi: x*W) ----
  {
    float2 xv[8], m[8];
    #pragma unroll
    for (int j = 0; j < 8; ++j) {
      int n = tid + 512 * j;
      xv[j] = make_float2(r0[n], r1[n]);
    }
    #pragma unroll
    for (int j = 0; j < 8; ++j) {
      float2 w = (j == 0) ? whi : cmul(whi, make_float2(C16x[j], C16y[j])); // W_8192^n
      m[j] = cmul(xv[j], w);
    }
    r8_fwd<false>(xv, bA);   // xv -> lo-half trip A output
    r8_fwd<false>(m, bA);    // m  -> hi-half trip A output
    #pragma unroll
    for (int j = 0; j < 8; ++j)
      cb[P(tid + 512 * j)] = make_float4(xv[j].x, xv[j].y, m[j].x, m[j].y);
  }
  __syncthreads();

  // ---- Phase 2: B on both halves ----
  d8f(cb, baseB, 64, bB);
  __syncthreads();

  // ---- Phase 3: T-hat prefetch (overlaps trip C), then C on both halves ----
  float4 thq[8];
  #pragma unroll
  for (int j = 0; j < 8; ++j) thq[j] = thg[tid + 512 * j];
  d8f(cb, baseC, 8, bC);
  __syncthreads();

  // ---- Phase 4: MID on both halves (unit fwd + That* + unit inv) ----
  {
    float2 lo[8], hi[8];
    #pragma unroll
    for (int j = 0; j < 8; ++j) {
      float4 q = cb[P(tid * 8 + j)];
      lo[j] = make_float2(q.x, q.y);
      hi[j] = make_float2(q.z, q.w);
    }
    r8_fwd<true>(lo, ONE);
    r8_fwd<true>(hi, ONE);
    #pragma unroll
    for (int j = 0; j < 8; ++j) {
      lo[j] = cmul(lo[j], make_float2(thq[j].x, thq[j].y));
      hi[j] = cmul(hi[j], make_float2(thq[j].z, thq[j].w));
    }
    r8_inv<true>(lo, ONE);
    r8_inv<true>(hi, ONE);
    #pragma unroll
    for (int j = 0; j < 8; ++j)
      cb[P(tid * 8 + j)] = make_float4(lo[j].x, lo[j].y, hi[j].x, hi[j].y);
  }
  __syncthreads();

  // ---- Phase 5: C' on both halves ----
  d8i(cb, baseC, 8, gC);
  __syncthreads();

  // ---- Phase 6: B' on both halves ----
  d8i(cb, baseB, 64, gB);
  __syncthreads();

  // ---- Phase 7: A' in registers on both halves + combine + store ----
  {
    float2 u[8], v[8];
    #pragma unroll
    for (int j = 0; j < 8; ++j) {
      float4 q = cb[P(tid + 512 * j)];
      u[j] = make_float2(q.x, q.y);
      v[j] = make_float2(q.z, q.w);
    }
    r8_inv<false>(u, gA);
    r8_inv<false>(v, gA);
    // final h=4096 inverse stage fused into the store: y = u + v*conj(W_8192^n)
    #pragma unroll
    for (int k = 0; k < 8; ++k) {
      float2 wc = (k == 0) ? whic : cmul(whic, make_float2(C16x[k], -C16y[k]));
      float2 t = cmul(v[k], wc);
      int n = tid + 512 * k;
      r0[n] = u[k].x + t.x;
      r1[n] = u[k].y + t.y;
    }
  }
}

// 64x64 tile transpose, 256 threads, float4 global I/O, padded LDS.
// At ~6.6 TB/s measured (R7) — HBM roofline; leave as is.
__global__ __launch_bounds__(256)
void transpose64(const float* __restrict__ src, float* __restrict__ dst, int R, int C) {
  __shared__ float tile[64][65];
  int t  = threadIdx.x;
  int c4 = t & 15;
  int r  = t >> 4;
  size_t slab = (size_t)blockIdx.z * (size_t)R * (size_t)C;
  const float* s = src + slab;
  float* dd = dst + slab;
  int col0 = blockIdx.x * 64, row0 = blockIdx.y * 64;
  #pragma unroll
  for (int k = 0; k < 4; ++k) {
    int rr = r + 16 * k;
    const float4 v = *(const float4*)(s + (size_t)(row0 + rr) * C + col0 + 4 * c4);
    tile[rr][4 * c4 + 0] = v.x;
    tile[rr][4 * c4 + 1] = v.y;
    tile[rr][4 * c4 + 2] = v.z;
    tile[rr][4 * c4 + 3] = v.w;
  }
  __syncthreads();
  #pragma unroll
  for (int k = 0; k < 4; ++k) {
    int cc = r + 16 * k;
    float4 w;
    w.x = tile[4 * c4 + 0][cc];
    w.y = tile[4 * c4 + 1][cc];
    w.z = tile[4 * c4 + 2][cc];
    w.w = tile[4 * c4 + 3][cc];
    *(float4*)(dd + (size_t)(col0 + cc) * R + row0 + 4 * c4) = w;
  }
}

extern "C" void kernel_launch(void* const* d_in, const int* in_sizes, int n_in,
                              void* d_out, int out_size, void* d_ws, size_t ws_size,
                              hipStream_t stream) {
  const float* x = (const float*)d_in[0];   // (4, 4096, 1024)
  const float* t = (const float*)d_in[1];   // (4096, 1024)
  float* out = (float*)d_out;               // (4, 4096, 1024) = 64 MB
  float* ws  = (float*)d_ws;
  float* xT  = ws;                                   // (4, 1024, 4096)  64 MB
  float* tT  = ws + (size_t)4 * 1024 * 4096;         // (1024, 4096)     16 MB
  // T-hat (interleaved lo/hi float4) lives in d_out: 1024*4096*16B = 64 MB
  // exactly; consumed by fftconv, then fully overwritten by the final transpose.
  float4* ThG = (float4*)d_out;

  transpose64<<<dim3(16, 64, 4), 256, 0, stream>>>(x, xT, 4096, 1024);
  transpose64<<<dim3(16, 64, 1), 256, 0, stream>>>(t, tT, 4096, 1024);

  that8h<<<dim3(1024), NT, 0, stream>>>(tT, ThG);
  fftconv<<<dim3(2, 1024), NT, 0, stream>>>(xT, ThG);

  transpose64<<<dim3(64, 16, 4), 256, 0, stream>>>(xT, out, 1024, 4096);
}

// Round 21
// 146.622 us; speedup vs baseline: 1.6974x; 1.0141x over previous
//
#include <hip/hip_runtime.h>

#define NT 512
#define SCL (1.0f / 8192.0f)
#define PI_F 3.14159265358979323846f

// XOR swizzle: bijective involution on [0,4096) float4 indices.
__device__ __forceinline__ int P(int i) { return i ^ ((i >> 5) & 31); }

__device__ __forceinline__ float2 cmul(float2 a, float2 b) {
  return make_float2(a.x * b.x - a.y * b.y, a.x * b.y + a.y * b.x);
}
__device__ __forceinline__ float2 csqr(float2 a) {
  return make_float2(a.x * a.x - a.y * a.y, 2.f * a.x * a.y);
}
__device__ __forceinline__ float2 cadd(float2 a, float2 b) { return make_float2(a.x + b.x, a.y + b.y); }
__device__ __forceinline__ float2 csub(float2 a, float2 b) { return make_float2(a.x - b.x, a.y - b.y); }
__device__ __forceinline__ float2 cmuli (float2 a) { return make_float2(-a.y,  a.x); } // *(+i)
__device__ __forceinline__ float2 cmulmi(float2 a) { return make_float2( a.y, -a.x); } // *(-i)

constexpr float RT2 = 0.70710678118654752440f;
constexpr float CQ1 = 0.92387953251128675613f; // cos(pi/8)
constexpr float SQ1 = 0.38268343236508977173f; // sin(pi/8)
// C8[k] = W8^k = e^{-i pi k/4}
constexpr float C8x[4] = {1.f,  RT2, 0.f, -RT2};
constexpr float C8y[4] = {0.f, -RT2, -1.f, -RT2};
// C16[k] = W16^k = e^{-i pi k/8} — used as W_8192^{512k} in the fused loads
constexpr float C16x[8] = {1.f,  CQ1,  RT2,  SQ1, 0.f, -SQ1, -RT2, -CQ1};
constexpr float C16y[8] = {0.f, -SQ1, -RT2, -CQ1, -1.f, -CQ1, -RT2, -SQ1};

// In-register 8-point DIF, stages at register strides 4,2,1 (R7/R14-verified).
// Stage stride s uses twiddle b^{4/s} * W_{2s}^{j mod s}; UNIT means b == 1.
template<bool UNIT>
__device__ __forceinline__ void r8_fwd(float2* e, float2 b) {
  float2 b2, b4;
  if (!UNIT) { b2 = csqr(b); b4 = csqr(b2); }
  #pragma unroll
  for (int j = 0; j < 4; ++j) {
    float2 u = e[j], v = e[j + 4];
    float2 d = csub(u, v);
    e[j] = cadd(u, v);
    float2 c8 = make_float2(C8x[j], C8y[j]);
    if (UNIT) e[j + 4] = (j == 0) ? d : cmul(d, c8);
    else      e[j + 4] = cmul(d, (j == 0) ? b : cmul(b, c8));
  }
  #pragma unroll
  for (int o = 0; o < 8; o += 4) {
    #pragma unroll
    for (int j = 0; j < 2; ++j) {
      float2 u = e[o + j], v = e[o + j + 2];
      float2 d = csub(u, v);
      e[o + j] = cadd(u, v);
      if (UNIT) e[o + j + 2] = (j == 0) ? d : cmulmi(d);
      else      e[o + j + 2] = cmul(d, (j == 0) ? b2 : cmulmi(b2));
    }
  }
  #pragma unroll
  for (int o = 0; o < 8; o += 2) {
    float2 u = e[o], v = e[o + 1];
    float2 d = csub(u, v);
    e[o] = cadd(u, v);
    e[o + 1] = UNIT ? d : cmul(d, b4);
  }
}

// In-register 8-point DIT inverse, stages at strides 1,2,4. g = conj(beta).
template<bool UNIT>
__device__ __forceinline__ void r8_inv(float2* e, float2 g) {
  float2 g2, g4;
  if (!UNIT) { g2 = csqr(g); g4 = csqr(g2); }
  #pragma unroll
  for (int o = 0; o < 8; o += 2) {
    float2 t = UNIT ? e[o + 1] : cmul(e[o + 1], g4);
    float2 u = e[o];
    e[o] = cadd(u, t); e[o + 1] = csub(u, t);
  }
  #pragma unroll
  for (int o = 0; o < 8; o += 4) {
    #pragma unroll
    for (int j = 0; j < 2; ++j) {
      float2 v = e[o + j + 2];
      float2 t;
      if (UNIT) t = (j == 0) ? v : cmuli(v);
      else      t = cmul(v, (j == 0) ? g2 : cmuli(g2));
      float2 u = e[o + j];
      e[o + j] = cadd(u, t); e[o + j + 2] = csub(u, t);
    }
  }
  #pragma unroll
  for (int j = 0; j < 4; ++j) {
    float2 v = e[j + 4];
    float2 t;
    float2 c8c = make_float2(C8x[j], -C8y[j]);
    if (UNIT) t = (j == 0) ? v : cmul(v, c8c);
    else      t = cmul(v, (j == 0) ? g : cmul(g, c8c));
    float2 u = e[j];
    e[j] = cadd(u, t); e[j + 4] = csub(u, t);
  }
}

// Dual radix-8 trips on the float4-packed buffer: .xy = lo half, .zw = hi half.
// One ds_read_b128/ds_write_b128 per element pair; twiddle regs shared.
__device__ __forceinline__ void d8f(float4* cb, int base, int G, float2 b) {
  float2 lo[8], hi[8];
  #pragma unroll
  for (int j = 0; j < 8; ++j) {
    float4 q = cb[P(base + G * j)];
    lo[j] = make_float2(q.x, q.y);
    hi[j] = make_float2(q.z, q.w);
  }
  r8_fwd<false>(lo, b);
  r8_fwd<false>(hi, b);
  #pragma unroll
  for (int j = 0; j < 8; ++j)
    cb[P(base + G * j)] = make_float4(lo[j].x, lo[j].y, hi[j].x, hi[j].y);
}

__device__ __forceinline__ void d8i(float4* cb, int base, int G, float2 g) {
  float2 lo[8], hi[8];
  #pragma unroll
  for (int j = 0; j < 8; ++j) {
    float4 q = cb[P(base + G * j)];
    lo[j] = make_float2(q.x, q.y);
    hi[j] = make_float2(q.z, q.w);
  }
  r8_inv<false>(lo, g);
  r8_inv<false>(hi, g);
  #pragma unroll
  for (int j = 0; j < 8; ++j)
    cb[P(base + G * j)] = make_float4(lo[j].x, lo[j].y, hi[j].x, hi[j].y);
}

// K2a: both T-hat halves in one WG, float4-packed (R17 structure + R18 pack).
// half-lo input = t[n]; half-hi = t[n]*W_8192^n. 4096 = 8^4: A(fused load),
// B(G=64), C(G=8), MID-fwd + scaled store interleaved:
// ThG4[d*4096 + tid + 512*j] = {T-lo, T-hi} (fftconv reads it back as float4).
__global__ __launch_bounds__(NT)
void that8h(const float* __restrict__ tT, float4* __restrict__ ThG) {
  __shared__ float4 cb[4096];   // 64 KiB packed
  const int tid = threadIdx.x;
  const int d = blockIdx.x;

  const int baseB = ((tid >> 6) << 9) + (tid & 63);
  const int baseC = ((tid >> 3) << 6) + (tid & 7);

  float s0, c0; __sincosf(-PI_F * (float)tid / 2048.f, &s0, &c0);
  const float2 bA = make_float2(c0, s0);            // W_4096^tid
  float s1, c1; __sincosf(-PI_F * (float)(tid & 63) / 256.f, &s1, &c1);
  const float2 bB = make_float2(c1, s1);            // W_512^(tid&63)
  float s2, c2; __sincosf(-PI_F * (float)(tid & 7) / 32.f, &s2, &c2);
  const float2 bC = make_float2(c2, s2);            // W_64^(tid&7)
  float sw, cw; __sincosf(-PI_F * (float)tid / 4096.f, &sw, &cw);
  const float2 whi = make_float2(cw, sw);           // W_8192^tid

  const float* tp = tT + (size_t)d * 4096;
  {
    float tv[8];
    #pragma unroll
    for (int j = 0; j < 8; ++j) tv[j] = tp[tid + 512 * j];
    float2 lo[8], hi[8];
    #pragma unroll
    for (int j = 0; j < 8; ++j) {
      lo[j] = make_float2(tv[j], 0.f);
      float2 w = (j == 0) ? whi : cmul(whi, make_float2(C16x[j], C16y[j])); // W_8192^n
      hi[j] = make_float2(tv[j] * w.x, tv[j] * w.y);
    }
    r8_fwd<false>(lo, bA);
    r8_fwd<false>(hi, bA);
    #pragma unroll
    for (int j = 0; j < 8; ++j)
      cb[P(tid + 512 * j)] = make_float4(lo[j].x, lo[j].y, hi[j].x, hi[j].y);
  }
  __syncthreads();
  d8f(cb, baseB, 64, bB);  __syncthreads();
  d8f(cb, baseC, 8, bC);   __syncthreads();
  {
    float2 lo[8], hi[8];
    #pragma unroll
    for (int j = 0; j < 8; ++j) {
      float4 q = cb[P(tid * 8 + j)];
      lo[j] = make_float2(q.x, q.y);
      hi[j] = make_float2(q.z, q.w);
    }
    r8_fwd<true>(lo, make_float2(1.f, 0.f));
    r8_fwd<true>(hi, make_float2(1.f, 0.f));
    float4* thg = ThG + (size_t)d * 4096;
    #pragma unroll
    for (int j = 0; j < 8; ++j)
      thg[tid + 512 * j] = make_float4(lo[j].x * SCL, lo[j].y * SCL,
                                       hi[j].x * SCL, hi[j].y * SCL);
  }
}

// K2b: one WG per (pass, channel d). R18-verified 7-phase structure; R21:
// thq prefetch hoisted to phase 2 (overlaps trips B AND C — ~2 phases of
// latency cover; phases 2-3 live set = d8f transients 32 + thq 32 + ambient
// ~24 ≈ 88 = the R18 VGPR count, no cap risk).
__global__ __launch_bounds__(NT)
void fftconv(float* __restrict__ xT, const float4* __restrict__ ThG) {
  __shared__ float4 cb[4096];   // 64 KiB packed: .xy lo half, .zw hi half
  const int tid = threadIdx.x;
  const int pass = blockIdx.x;
  const int d = blockIdx.y;

  const int baseB = ((tid >> 6) << 9) + (tid & 63);
  const int baseC = ((tid >> 3) << 6) + (tid & 7);
  const float2 ONE = make_float2(1.f, 0.f);

  float s0, c0; __sincosf(-PI_F * (float)tid / 2048.f, &s0, &c0);
  const float2 bA = make_float2(c0, s0);            // W_4096^tid
  const float2 gA = make_float2(c0, -s0);
  float s1, c1; __sincosf(-PI_F * (float)(tid & 63) / 256.f, &s1, &c1);
  const float2 bB = make_float2(c1, s1);            // W_512^(tid&63)
  const float2 gB = make_float2(c1, -s1);
  float s2, c2; __sincosf(-PI_F * (float)(tid & 7) / 32.f, &s2, &c2);
  const float2 bC = make_float2(c2, s2);            // W_64^(tid&7)
  const float2 gC = make_float2(c2, -s2);
  float sw, cw; __sincosf(-PI_F * (float)tid / 4096.f, &sw, &cw);
  const float2 whi  = make_float2(cw, sw);          // W_8192^tid
  const float2 whic = make_float2(cw, -sw);

  float* r0 = xT + ((size_t)(2 * pass)     * 1024 + d) * 4096;
  float* r1 = xT + ((size_t)(2 * pass + 1) * 1024 + d) * 4096;
  const float4* thg = ThG + (size_t)d * 4096;

  // ---- Phase 1: load x ONCE; trip A on both halves (lo: x, hi: x*W) ----
  {
    float2 xv[8], m[8];
    #pragma unroll
    for (int j = 0; j < 8; ++j) {
      int n = tid + 512 * j;
      xv[j] = make_float2(r0[n], r1[n]);
    }
    #pragma unroll
    for (int j = 0; j < 8; ++j) {
      float2 w = (j == 0) ? whi : cmul(whi, make_float2(C16x[j], C16y[j])); // W_8192^n
      m[j] = cmul(xv[j], w);
    }
    r8_fwd<false>(xv, bA);   // xv -> lo-half trip A output
    r8_fwd<false>(m, bA);    // m  -> hi-half trip A output
    #pragma unroll
    for (int j = 0; j < 8; ++j)
      cb[P(tid + 512 * j)] = make_float4(xv[j].x, xv[j].y, m[j].x, m[j].y);
  }
  __syncthreads();

  // ---- Phase 2: T-hat prefetch (overlaps trips B and C), then B ----
  float4 thq[8];
  #pragma unroll
  for (int j = 0; j < 8; ++j) thq[j] = thg[tid + 512 * j];
  d8f(cb, baseB, 64, bB);
  __syncthreads();

  // ---- Phase 3: C on both halves ----
  d8f(cb, baseC, 8, bC);
  __syncthreads();

  // ---- Phase 4: MID on both halves (unit fwd + That* + unit inv) ----
  {
    float2 lo[8], hi[8];
    #pragma unroll
    for (int j = 0; j < 8; ++j) {
      float4 q = cb[P(tid * 8 + j)];
      lo[j] = make_float2(q.x, q.y);
      hi[j] = make_float2(q.z, q.w);
    }
    r8_fwd<true>(lo, ONE);
    r8_fwd<true>(hi, ONE);
    #pragma unroll
    for (int j = 0; j < 8; ++j) {
      lo[j] = cmul(lo[j], make_float2(thq[j].x, thq[j].y));
      hi[j] = cmul(hi[j], make_float2(thq[j].z, thq[j].w));
    }
    r8_inv<true>(lo, ONE);
    r8_inv<true>(hi, ONE);
    #pragma unroll
    for (int j = 0; j < 8; ++j)
      cb[P(tid * 8 + j)] = make_float4(lo[j].x, lo[j].y, hi[j].x, hi[j].y);
  }
  __syncthreads();

  // ---- Phase 5: C' on both halves ----
  d8i(cb, baseC, 8, gC);
  __syncthreads();

  // ---- Phase 6: B' on both halves ----
  d8i(cb, baseB, 64, gB);
  __syncthreads();

  // ---- Phase 7: A' in registers on both halves + combine + store ----
  {
    float2 u[8], v[8];
    #pragma unroll
    for (int j = 0; j < 8; ++j) {
      float4 q = cb[P(tid + 512 * j)];
      u[j] = make_float2(q.x, q.y);
      v[j] = make_float2(q.z, q.w);
    }
    r8_inv<false>(u, gA);
    r8_inv<false>(v, gA);
    // final h=4096 inverse stage fused into the store: y = u + v*conj(W_8192^n)
    #pragma unroll
    for (int k = 0; k < 8; ++k) {
      float2 wc = (k == 0) ? whic : cmul(whic, make_float2(C16x[k], -C16y[k]));
      float2 t = cmul(v[k], wc);
      int n = tid + 512 * k;
      r0[n] = u[k].x + t.x;
      r1[n] = u[k].y + t.y;
    }
  }
}

// 64x64 tile transpose, 256 threads, float4 global I/O, padded LDS.
// At ~6.6 TB/s measured — HBM roofline. R21: the input variant handles BOTH
// x (slabs z<4) and t (z==4) in one launch (same R=4096, C=1024 geometry).
__global__ __launch_bounds__(256)
void transpose_in(const float* __restrict__ x, float* __restrict__ xT,
                  const float* __restrict__ t, float* __restrict__ tT) {
  __shared__ float tile[64][65];
  int th = threadIdx.x;
  int c4 = th & 15;
  int r  = th >> 4;
  const int R = 4096, C = 1024;
  int z = blockIdx.z;
  const float* s = (z < 4) ? x + (size_t)z * R * C : t;
  float* dd      = (z < 4) ? xT + (size_t)z * R * C : tT;
  int col0 = blockIdx.x * 64, row0 = blockIdx.y * 64;
  #pragma unroll
  for (int k = 0; k < 4; ++k) {
    int rr = r + 16 * k;
    const float4 v = *(const float4*)(s + (size_t)(row0 + rr) * C + col0 + 4 * c4);
    tile[rr][4 * c4 + 0] = v.x;
    tile[rr][4 * c4 + 1] = v.y;
    tile[rr][4 * c4 + 2] = v.z;
    tile[rr][4 * c4 + 3] = v.w;
  }
  __syncthreads();
  #pragma unroll
  for (int k = 0; k < 4; ++k) {
    int cc = r + 16 * k;
    float4 w;
    w.x = tile[4 * c4 + 0][cc];
    w.y = tile[4 * c4 + 1][cc];
    w.z = tile[4 * c4 + 2][cc];
    w.w = tile[4 * c4 + 3][cc];
    *(float4*)(dd + (size_t)(col0 + cc) * R + row0 + 4 * c4) = w;
  }
}

// Output transpose: (1024, 4096) -> (4096, 1024) per slab.
__global__ __launch_bounds__(256)
void transpose64(const float* __restrict__ src, float* __restrict__ dst, int R, int C) {
  __shared__ float tile[64][65];
  int th = threadIdx.x;
  int c4 = th & 15;
  int r  = th >> 4;
  size_t slab = (size_t)blockIdx.z * (size_t)R * (size_t)C;
  const float* s = src + slab;
  float* dd = dst + slab;
  int col0 = blockIdx.x * 64, row0 = blockIdx.y * 64;
  #pragma unroll
  for (int k = 0; k < 4; ++k) {
    int rr = r + 16 * k;
    const float4 v = *(const float4*)(s + (size_t)(row0 + rr) * C + col0 + 4 * c4);
    tile[rr][4 * c4 + 0] = v.x;
    tile[rr][4 * c4 + 1] = v.y;
    tile[rr][4 * c4 + 2] = v.z;
    tile[rr][4 * c4 + 3] = v.w;
  }
  __syncthreads();
  #pragma unroll
  for (int k = 0; k < 4; ++k) {
    int cc = r + 16 * k;
    float4 w;
    w.x = tile[4 * c4 + 0][cc];
    w.y = tile[4 * c4 + 1][cc];
    w.z = tile[4 * c4 + 2][cc];
    w.w = tile[4 * c4 + 3][cc];
    *(float4*)(dd + (size_t)(col0 + cc) * R + row0 + 4 * c4) = w;
  }
}

extern "C" void kernel_launch(void* const* d_in, const int* in_sizes, int n_in,
                              void* d_out, int out_size, void* d_ws, size_t ws_size,
                              hipStream_t stream) {
  const float* x = (const float*)d_in[0];   // (4, 4096, 1024)
  const float* t = (const float*)d_in[1];   // (4096, 1024)
  float* out = (float*)d_out;               // (4, 4096, 1024) = 64 MB
  float* ws  = (float*)d_ws;
  float* xT  = ws;                                   // (4, 1024, 4096)  64 MB
  float* tT  = ws + (size_t)4 * 1024 * 4096;         // (1024, 4096)     16 MB
  // T-hat (interleaved lo/hi float4) lives in d_out: 1024*4096*16B = 64 MB
  // exactly; consumed by fftconv, then fully overwritten by the final transpose.
  float4* ThG = (float4*)d_out;

  transpose_in<<<dim3(16, 64, 5), 256, 0, stream>>>(x, xT, t, tT);

  that8h<<<dim3(1024), NT, 0, stream>>>(tT, ThG);
  fftconv<<<dim3(2, 1024), NT, 0, stream>>>(xT, ThG);

  transpose64<<<dim3(64, 16, 4), 256, 0, stream>>>(xT, out, 1024, 4096);
}